// Round 1
// baseline (277.945 us; speedup 1.0000x reference)
//
#include <hip/hip_runtime.h>
#include <hip/hip_bf16.h>

// DiscoMixerBlock: B=1, H=90, W=180 (P=16200), MODEL_DIM=130 (L=128),
// NH=8, HD=16, S=16, K=25, NNB=25, MH=32, FH=256. All fp32.
#define P_TOT 16200
#define MODEL_DIMC 130
#define L_DIM 128
#define NHH 8
#define HDD 16
#define S_DIM 16
#define K_DIM 25
#define NNBC 25
#define MH_DIM 32
#define FH_DIM 256

// exact gelu: x * 0.5 * (1 + erf(x/sqrt(2))); erf via Abramowitz-Stegun 7.1.26 (|err|<=1.5e-7)
__device__ __forceinline__ float gelu_f(float x) {
    float z = fabsf(x) * 0.70710678118654752440f;
    float t = __fdividef(1.0f, fmaf(0.3275911f, z, 1.0f));
    float poly = t * fmaf(t, fmaf(t, fmaf(t, fmaf(t, 1.061405429f, -1.453152027f),
                                          1.421413741f), -0.284496736f), 0.254829592f);
    float e = __expf(-z * z);
    float erfp = fmaf(-poly, e, 1.0f);     // erf(|x|/sqrt2), >=0
    float erfv = copysignf(erfp, x);
    return 0.5f * x * (1.0f + erfv);
}

// ---------------- K1: bw[p][n][s] = sum_k disco_w[s][k] * basis[k][p][n] ----------------
__global__ __launch_bounds__(256) void k1_bw(const float* __restrict__ basis,
                                             const float* __restrict__ disco_w,
                                             float* __restrict__ bw) {
    __shared__ float w[S_DIM * K_DIM];   // [s][k]
    int tid = threadIdx.x;
    for (int i = tid; i < S_DIM * K_DIM; i += 256) w[i] = disco_w[i];
    __syncthreads();
    int i = blockIdx.x * 256 + tid;      // flat (p,n)
    if (i >= P_TOT * NNBC) return;
    float bv[K_DIM];
#pragma unroll
    for (int k = 0; k < K_DIM; k++) bv[k] = basis[k * (P_TOT * NNBC) + i];
    float acc[S_DIM];
#pragma unroll
    for (int s = 0; s < S_DIM; s++) {
        float a = 0.f;
#pragma unroll
        for (int k = 0; k < K_DIM; k++) a = fmaf(w[s * K_DIM + k], bv[k], a);
        acc[s] = a;
    }
    float4* outp = (float4*)(bw + (size_t)i * S_DIM);
#pragma unroll
    for (int q = 0; q < 4; q++) {
        float4 v; v.x = acc[q*4+0]; v.y = acc[q*4+1]; v.z = acc[q*4+2]; v.w = acc[q*4+3];
        outp[q] = v;
    }
}

// ---------------- K2: fused disco gather-dot + head MLP + residual -> xmix[p][c] ----------------
// one wave per point; lane owns channels c0=lane, c1=lane+64
__global__ __launch_bounds__(256) void k2_disco_head(
        const float* __restrict__ x, const int* __restrict__ nbr,
        const float* __restrict__ bw,
        const float* __restrict__ head_w1, const float* __restrict__ head_b1,
        const float* __restrict__ head_w2, const float* __restrict__ head_b2,
        const float* __restrict__ disco_b,
        float* __restrict__ xmix) {
    // padded strides (516, 33) so the 4 distinct h-addresses per wave land in different banks
    __shared__ __align__(16) float w1t[NHH * 516];        // [h][m][s] (s contiguous), stride 516/h
    __shared__ float b1s[NHH * 33];
    __shared__ float w2s[NHH * 33];
    __shared__ float b2s[NHH];
    __shared__ float dbs[S_DIM];
    __shared__ __align__(16) float bws[4][NNBC * S_DIM];  // per-wave point: [n][s]
    __shared__ int nbrs[4][NNBC];

    int tid = threadIdx.x;
    for (int i = tid; i < NHH * S_DIM * MH_DIM; i += 256) {
        int h = i >> 9, s = (i >> 5) & 15, m = i & 31;    // global layout [h][s][m]
        w1t[h * 516 + m * 16 + s] = head_w1[i];
    }
    for (int i = tid; i < NHH * MH_DIM; i += 256) {
        int h = i >> 5, m = i & 31;
        b1s[h * 33 + m] = head_b1[i];
        w2s[h * 33 + m] = head_w2[i];                     // head_w2[h][m][0]
    }
    if (tid < NHH) b2s[tid] = head_b2[tid];
    if (tid < S_DIM) dbs[tid] = disco_b[tid];

    int wv = tid >> 6, lane = tid & 63;
    int p = blockIdx.x * 4 + wv;
    if (lane < NNBC) nbrs[wv][lane] = nbr[p * NNBC + lane];
    {
        const float4* src = (const float4*)(bw + (size_t)p * (NNBC * S_DIM));
        float4* dst = (float4*)bws[wv];
        for (int j = lane; j < (NNBC * S_DIM) / 4; j += 64) dst[j] = src[j];
    }
    __syncthreads();

    float y0[16], y1[16];
#pragma unroll
    for (int s = 0; s < 16; s++) { y0[s] = dbs[s]; y1[s] = dbs[s]; }

    const float* xb0 = x + lane;
    const float* xb1 = x + 64 + lane;
#pragma unroll 5
    for (int n = 0; n < NNBC; n++) {
        int u = nbrs[wv][n];
        float g0 = xb0[u * MODEL_DIMC];
        float g1 = xb1[u * MODEL_DIMC];
        const float4* bwn = (const float4*)&bws[wv][n * 16];
#pragma unroll
        for (int q = 0; q < 4; q++) {
            float4 b4 = bwn[q];
            y0[q*4+0] = fmaf(g0, b4.x, y0[q*4+0]);
            y0[q*4+1] = fmaf(g0, b4.y, y0[q*4+1]);
            y0[q*4+2] = fmaf(g0, b4.z, y0[q*4+2]);
            y0[q*4+3] = fmaf(g0, b4.w, y0[q*4+3]);
            y1[q*4+0] = fmaf(g1, b4.x, y1[q*4+0]);
            y1[q*4+1] = fmaf(g1, b4.y, y1[q*4+1]);
            y1[q*4+2] = fmaf(g1, b4.z, y1[q*4+2]);
            y1[q*4+3] = fmaf(g1, b4.w, y1[q*4+3]);
        }
    }

    // head MLP: c0 -> h0 = lane>>4 (0..3), c1 -> h1 = h0+4
    int h0 = lane >> 4, h1 = h0 + 4;
    float acc0 = b2s[h0], acc1 = b2s[h1];
    const float* w1t0 = &w1t[h0 * 516];
    const float* w1t1 = &w1t[h1 * 516];
#pragma unroll 8
    for (int m = 0; m < MH_DIM; m++) {
        float a0 = b1s[h0 * 33 + m], a1 = b1s[h1 * 33 + m];
        const float4* r0 = (const float4*)&w1t0[m * 16];
        const float4* r1 = (const float4*)&w1t1[m * 16];
#pragma unroll
        for (int q = 0; q < 4; q++) {
            float4 wa = r0[q];
            a0 = fmaf(y0[q*4+0], wa.x, a0);
            a0 = fmaf(y0[q*4+1], wa.y, a0);
            a0 = fmaf(y0[q*4+2], wa.z, a0);
            a0 = fmaf(y0[q*4+3], wa.w, a0);
            float4 wb = r1[q];
            a1 = fmaf(y1[q*4+0], wb.x, a1);
            a1 = fmaf(y1[q*4+1], wb.y, a1);
            a1 = fmaf(y1[q*4+2], wb.z, a1);
            a1 = fmaf(y1[q*4+3], wb.w, a1);
        }
        a0 = gelu_f(a0);
        a1 = gelu_f(a1);
        acc0 = fmaf(a0, w2s[h0 * 33 + m], acc0);
        acc1 = fmaf(a1, w2s[h1 * 33 + m], acc1);
    }
    // residual (x_res = x_learn)
    float xm0 = acc0 + x[p * MODEL_DIMC + lane];
    float xm1 = acc1 + x[p * MODEL_DIMC + 64 + lane];
    xmix[p * L_DIM + lane] = xm0;
    xmix[p * L_DIM + 64 + lane] = xm1;
}

// ---------------- K3: FFN over x_full = [xmix, sin_cos]; w1 rows 128..129 are zero ----------------
// block = 256 threads handles 32 points
__global__ __launch_bounds__(256) void k3_ffn(
        const float* __restrict__ x, const float* __restrict__ xmix,
        const float* __restrict__ w1, const float* __restrict__ b1,
        const float* __restrict__ w2, const float* __restrict__ b2,
        float* __restrict__ out) {
    __shared__ __align__(16) float xm[32 * 128];
    __shared__ __align__(16) float hf[32 * 260];   // padded stride 260
    int tid = threadIdx.x;
    int p0 = blockIdx.x * 32;
    int valid = min(32, P_TOT - p0);
    {
        int nf4 = (valid * 128) / 4;
        const float4* src = (const float4*)(xmix + (size_t)p0 * 128);
        float4* dst = (float4*)xm;
        for (int j = tid; j < nf4; j += 256) dst[j] = src[j];
    }
    __syncthreads();

    int fg = tid & 31, pg = tid >> 5;              // fg: 8 f-outputs, pg: 4 points
    float acc[4][8];
#pragma unroll
    for (int i = 0; i < 4; i++)
#pragma unroll
        for (int j = 0; j < 8; j++) acc[i][j] = b1[fg * 8 + j];

#pragma unroll 4
    for (int k = 0; k < 128; k++) {
        float4 wA = *(const float4*)&w1[k * FH_DIM + fg * 8];
        float4 wB = *(const float4*)&w1[k * FH_DIM + fg * 8 + 4];
#pragma unroll
        for (int i = 0; i < 4; i++) {
            float xv = xm[(pg * 4 + i) * 128 + k];
            acc[i][0] = fmaf(xv, wA.x, acc[i][0]);
            acc[i][1] = fmaf(xv, wA.y, acc[i][1]);
            acc[i][2] = fmaf(xv, wA.z, acc[i][2]);
            acc[i][3] = fmaf(xv, wA.w, acc[i][3]);
            acc[i][4] = fmaf(xv, wB.x, acc[i][4]);
            acc[i][5] = fmaf(xv, wB.y, acc[i][5]);
            acc[i][6] = fmaf(xv, wB.z, acc[i][6]);
            acc[i][7] = fmaf(xv, wB.w, acc[i][7]);
        }
    }
#pragma unroll
    for (int i = 0; i < 4; i++) {
        int pl = pg * 4 + i;
#pragma unroll
        for (int j = 0; j < 8; j++) hf[pl * 260 + fg * 8 + j] = gelu_f(acc[i][j]);
    }
    __syncthreads();

    int lg = tid & 31;                              // 4 l-outputs each
    float acc2[4][4];
#pragma unroll
    for (int i = 0; i < 4; i++)
#pragma unroll
        for (int j = 0; j < 4; j++) acc2[i][j] = b2[lg * 4 + j];

#pragma unroll 4
    for (int f = 0; f < FH_DIM; f++) {
        float4 wv = *(const float4*)&w2[f * L_DIM + lg * 4];
#pragma unroll
        for (int i = 0; i < 4; i++) {
            float hv = hf[(pg * 4 + i) * 260 + f];
            acc2[i][0] = fmaf(hv, wv.x, acc2[i][0]);
            acc2[i][1] = fmaf(hv, wv.y, acc2[i][1]);
            acc2[i][2] = fmaf(hv, wv.z, acc2[i][2]);
            acc2[i][3] = fmaf(hv, wv.w, acc2[i][3]);
        }
    }
#pragma unroll
    for (int i = 0; i < 4; i++) {
        int pl = pg * 4 + i;
        if (pl < valid) {
            int p = p0 + pl;
            // x_out = x_ffn + x_mix (130-float rows are only 8B-aligned at l*4 -> float2 stores)
            float2 o01, o23;
            o01.x = acc2[i][0] + xm[pl * 128 + lg * 4 + 0];
            o01.y = acc2[i][1] + xm[pl * 128 + lg * 4 + 1];
            o23.x = acc2[i][2] + xm[pl * 128 + lg * 4 + 2];
            o23.y = acc2[i][3] + xm[pl * 128 + lg * 4 + 3];
            *(float2*)&out[p * MODEL_DIMC + lg * 4 + 0] = o01;
            *(float2*)&out[p * MODEL_DIMC + lg * 4 + 2] = o23;
            if (lg == 0) {
                float2 sc;
                sc.x = x[p * MODEL_DIMC + 128];
                sc.y = x[p * MODEL_DIMC + 129];
                *(float2*)&out[p * MODEL_DIMC + 128] = sc;
            }
        }
    }
}

extern "C" void kernel_launch(void* const* d_in, const int* in_sizes, int n_in,
                              void* d_out, int out_size, void* d_ws, size_t ws_size,
                              hipStream_t stream) {
    const float* x        = (const float*)d_in[0];
    const int*   nbr      = (const int*)  d_in[1];
    const float* basis    = (const float*)d_in[2];
    const float* disco_w  = (const float*)d_in[3];
    const float* disco_b  = (const float*)d_in[4];
    const float* head_w1  = (const float*)d_in[5];
    const float* head_b1  = (const float*)d_in[6];
    const float* head_w2  = (const float*)d_in[7];
    const float* head_b2  = (const float*)d_in[8];
    const float* ffn_w1   = (const float*)d_in[9];
    const float* ffn_b1   = (const float*)d_in[10];
    const float* ffn_w2   = (const float*)d_in[11];
    const float* ffn_b2   = (const float*)d_in[12];
    float* out = (float*)d_out;

    float* bw   = (float*)d_ws;                                   // [P][NNB][S] = 25.9 MB
    float* xmix = bw + (size_t)P_TOT * NNBC * S_DIM;              // [P][128]    = 8.3 MB

    hipLaunchKernelGGL(k1_bw, dim3((P_TOT * NNBC + 255) / 256), dim3(256), 0, stream,
                       basis, disco_w, bw);
    hipLaunchKernelGGL(k2_disco_head, dim3(P_TOT / 4), dim3(256), 0, stream,
                       x, nbr, bw, head_w1, head_b1, head_w2, head_b2, disco_b, xmix);
    hipLaunchKernelGGL(k3_ffn, dim3((P_TOT + 31) / 32), dim3(256), 0, stream,
                       x, xmix, ffn_w1, ffn_b1, ffn_w2, ffn_b2, out);
}

// Round 2
// 259.651 us; speedup vs baseline: 1.0705x; 1.0705x over previous
//
#include <hip/hip_runtime.h>
#include <hip/hip_bf16.h>

// DiscoMixerBlock: B=1, H=90, W=180 (P=16200), MODEL_DIM=130 (L=128),
// NH=8, HD=16, S=16, K=25, NNB=25, MH=32, FH=256. All fp32.
#define P_TOT 16200
#define MODEL_DIMC 130
#define L_DIM 128
#define NHH 8
#define HDD 16
#define S_DIM 16
#define K_DIM 25
#define NNBC 25
#define MH_DIM 32
#define FH_DIM 256

// exact gelu: x * 0.5 * (1 + erf(x/sqrt(2))); erf via Abramowitz-Stegun 7.1.26 (|err|<=1.5e-7)
__device__ __forceinline__ float gelu_f(float x) {
    float z = fabsf(x) * 0.70710678118654752440f;
    float t = __builtin_amdgcn_rcpf(fmaf(0.3275911f, z, 1.0f));
    float poly = t * fmaf(t, fmaf(t, fmaf(t, fmaf(t, 1.061405429f, -1.453152027f),
                                          1.421413741f), -0.284496736f), 0.254829592f);
    float e = __expf(-z * z);
    float erfp = fmaf(-poly, e, 1.0f);     // erf(|x|/sqrt2), >=0
    float erfv = copysignf(erfp, x);
    return 0.5f * x * (1.0f + erfv);
}

// ---------------- K1: bw[p][n][s] = sum_k disco_w[s][k] * basis[k][p][n] ----------------
__global__ __launch_bounds__(256) void k1_bw(const float* __restrict__ basis,
                                             const float* __restrict__ disco_w,
                                             float* __restrict__ bw) {
    __shared__ float w[S_DIM * K_DIM];   // [s][k]
    int tid = threadIdx.x;
    for (int i = tid; i < S_DIM * K_DIM; i += 256) w[i] = disco_w[i];
    __syncthreads();
    int i = blockIdx.x * 256 + tid;      // flat (p,n)
    if (i >= P_TOT * NNBC) return;
    float bv[K_DIM];
#pragma unroll
    for (int k = 0; k < K_DIM; k++) bv[k] = basis[k * (P_TOT * NNBC) + i];
    float acc[S_DIM];
#pragma unroll
    for (int s = 0; s < S_DIM; s++) {
        float a = 0.f;
#pragma unroll
        for (int k = 0; k < K_DIM; k++) a = fmaf(w[s * K_DIM + k], bv[k], a);
        acc[s] = a;
    }
    float4* outp = (float4*)(bw + (size_t)i * S_DIM);
#pragma unroll
    for (int q = 0; q < 4; q++) {
        float4 v; v.x = acc[q*4+0]; v.y = acc[q*4+1]; v.z = acc[q*4+2]; v.w = acc[q*4+3];
        outp[q] = v;
    }
}

// ---------------- K2: fused disco gather-dot + head MLP + residual -> xmix[p][c] ----------------
// 2 waves per point; each lane owns ONE channel c = (wv&1)*64 + lane.
// Per-lane live state: y[16] + ~8 temps -> fits 64-VGPR / 8-waves-per-EU with no spill.
__global__ __launch_bounds__(256) void k2_disco_head(
        const float* __restrict__ x, const int* __restrict__ nbr,
        const float* __restrict__ bw,
        const float* __restrict__ head_w1, const float* __restrict__ head_b1,
        const float* __restrict__ head_w2, const float* __restrict__ head_b2,
        const float* __restrict__ disco_b,
        float* __restrict__ xmix) {
    // padded strides (516, 33) so the 4 distinct h-addresses per wave land in different banks
    __shared__ __align__(16) float w1t[NHH * 516];        // [h][m][s] (s contiguous), stride 516
    __shared__ float b1s[NHH * 33];
    __shared__ float w2s[NHH * 33];
    __shared__ float b2s[NHH];
    __shared__ float dbs[S_DIM];
    __shared__ __align__(16) float bws[2][NNBC * S_DIM];  // per point: [n][s]
    __shared__ int nbrs[2][NNBC];

    int tid = threadIdx.x;
    for (int i = tid; i < NHH * S_DIM * MH_DIM; i += 256) {
        int h = i >> 9, s = (i >> 5) & 15, m = i & 31;    // global layout [h][s][m]
        w1t[h * 516 + m * 16 + s] = head_w1[i];
    }
    for (int i = tid; i < NHH * MH_DIM; i += 256) {
        int h = i >> 5, m = i & 31;
        b1s[h * 33 + m] = head_b1[i];
        w2s[h * 33 + m] = head_w2[i];                     // head_w2[h][m][0]
    }
    if (tid < NHH) b2s[tid] = head_b2[tid];
    if (tid < S_DIM) dbs[tid] = disco_b[tid];

    int p0 = blockIdx.x * 2;
    // bw rows for the block's 2 points are contiguous: 800 floats = 200 float4
    {
        const float4* src = (const float4*)(bw + (size_t)p0 * (NNBC * S_DIM));
        float4* dst = (float4*)&bws[0][0];
        for (int j = tid; j < (2 * NNBC * S_DIM) / 4; j += 256) dst[j] = src[j];
    }
    if (tid < 2 * NNBC) nbrs[0][tid] = nbr[p0 * NNBC + tid];   // [2][25] contiguous
    __syncthreads();

    int wv = tid >> 6, lane = tid & 63;
    int ptl = wv >> 1;                    // 0..1 local point
    int c = (wv & 1) * 64 + lane;         // channel 0..127
    int p = p0 + ptl;

    float y[16];
#pragma unroll
    for (int s = 0; s < 16; s++) y[s] = dbs[s];

    const float* xb = x + c;
#pragma unroll 5
    for (int nb = 0; nb < NNBC; nb += 5) {
        float g[5];
#pragma unroll
        for (int j = 0; j < 5; j++) {
            int u = nbrs[ptl][nb + j];
            g[j] = xb[(size_t)u * MODEL_DIMC];
        }
#pragma unroll
        for (int j = 0; j < 5; j++) {
            const float4* bwn = (const float4*)&bws[ptl][(nb + j) * 16];
#pragma unroll
            for (int q = 0; q < 4; q++) {
                float4 b4 = bwn[q];
                y[q*4+0] = fmaf(g[j], b4.x, y[q*4+0]);
                y[q*4+1] = fmaf(g[j], b4.y, y[q*4+1]);
                y[q*4+2] = fmaf(g[j], b4.z, y[q*4+2]);
                y[q*4+3] = fmaf(g[j], b4.w, y[q*4+3]);
            }
        }
    }

    // head MLP for this channel: h = c>>4
    int h = c >> 4;
    float acc = b2s[h];
    const float* wrow = &w1t[h * 516];
    const float* b1r  = &b1s[h * 33];
    const float* w2r  = &w2s[h * 33];
#pragma unroll 4
    for (int m = 0; m < MH_DIM; m++) {
        float a = b1r[m];
        const float4* r = (const float4*)&wrow[m * 16];
#pragma unroll
        for (int q = 0; q < 4; q++) {
            float4 wa = r[q];
            a = fmaf(y[q*4+0], wa.x, a);
            a = fmaf(y[q*4+1], wa.y, a);
            a = fmaf(y[q*4+2], wa.z, a);
            a = fmaf(y[q*4+3], wa.w, a);
        }
        a = gelu_f(a);
        acc = fmaf(a, w2r[m], acc);
    }
    // residual (x_res = x_learn)
    xmix[p * L_DIM + c] = acc + x[(size_t)p * MODEL_DIMC + c];
}

// ---------------- K3: FFN over x_full = [xmix, sin_cos]; w1 rows 128..129 are zero ----------------
// block = 256 threads handles 32 points
__global__ __launch_bounds__(256) void k3_ffn(
        const float* __restrict__ x, const float* __restrict__ xmix,
        const float* __restrict__ w1, const float* __restrict__ b1,
        const float* __restrict__ w2, const float* __restrict__ b2,
        float* __restrict__ out) {
    __shared__ __align__(16) float xm[32 * 128];
    __shared__ __align__(16) float hf[32 * 260];   // padded stride 260
    int tid = threadIdx.x;
    int p0 = blockIdx.x * 32;
    int valid = min(32, P_TOT - p0);
    {
        int nf4 = (valid * 128) / 4;
        const float4* src = (const float4*)(xmix + (size_t)p0 * 128);
        float4* dst = (float4*)xm;
        for (int j = tid; j < nf4; j += 256) dst[j] = src[j];
    }
    __syncthreads();

    int fg = tid & 31, pg = tid >> 5;              // fg: 8 f-outputs, pg: 4 points
    float acc[4][8];
#pragma unroll
    for (int i = 0; i < 4; i++)
#pragma unroll
        for (int j = 0; j < 8; j++) acc[i][j] = b1[fg * 8 + j];

#pragma unroll 4
    for (int k = 0; k < 128; k++) {
        float4 wA = *(const float4*)&w1[k * FH_DIM + fg * 8];
        float4 wB = *(const float4*)&w1[k * FH_DIM + fg * 8 + 4];
#pragma unroll
        for (int i = 0; i < 4; i++) {
            float xv = xm[(pg * 4 + i) * 128 + k];
            acc[i][0] = fmaf(xv, wA.x, acc[i][0]);
            acc[i][1] = fmaf(xv, wA.y, acc[i][1]);
            acc[i][2] = fmaf(xv, wA.z, acc[i][2]);
            acc[i][3] = fmaf(xv, wA.w, acc[i][3]);
            acc[i][4] = fmaf(xv, wB.x, acc[i][4]);
            acc[i][5] = fmaf(xv, wB.y, acc[i][5]);
            acc[i][6] = fmaf(xv, wB.z, acc[i][6]);
            acc[i][7] = fmaf(xv, wB.w, acc[i][7]);
        }
    }
#pragma unroll
    for (int i = 0; i < 4; i++) {
        int pl = pg * 4 + i;
#pragma unroll
        for (int j = 0; j < 8; j++) hf[pl * 260 + fg * 8 + j] = gelu_f(acc[i][j]);
    }
    __syncthreads();

    int lg = tid & 31;                              // 4 l-outputs each
    float acc2[4][4];
#pragma unroll
    for (int i = 0; i < 4; i++)
#pragma unroll
        for (int j = 0; j < 4; j++) acc2[i][j] = b2[lg * 4 + j];

#pragma unroll 4
    for (int f = 0; f < FH_DIM; f++) {
        float4 wv = *(const float4*)&w2[f * L_DIM + lg * 4];
#pragma unroll
        for (int i = 0; i < 4; i++) {
            float hv = hf[(pg * 4 + i) * 260 + f];
            acc2[i][0] = fmaf(hv, wv.x, acc2[i][0]);
            acc2[i][1] = fmaf(hv, wv.y, acc2[i][1]);
            acc2[i][2] = fmaf(hv, wv.z, acc2[i][2]);
            acc2[i][3] = fmaf(hv, wv.w, acc2[i][3]);
        }
    }
#pragma unroll
    for (int i = 0; i < 4; i++) {
        int pl = pg * 4 + i;
        if (pl < valid) {
            int p = p0 + pl;
            // x_out = x_ffn + x_mix (130-float rows are only 8B-aligned at l*4 -> float2 stores)
            float2 o01, o23;
            o01.x = acc2[i][0] + xm[pl * 128 + lg * 4 + 0];
            o01.y = acc2[i][1] + xm[pl * 128 + lg * 4 + 1];
            o23.x = acc2[i][2] + xm[pl * 128 + lg * 4 + 2];
            o23.y = acc2[i][3] + xm[pl * 128 + lg * 4 + 3];
            *(float2*)&out[p * MODEL_DIMC + lg * 4 + 0] = o01;
            *(float2*)&out[p * MODEL_DIMC + lg * 4 + 2] = o23;
            if (lg == 0) {
                float2 sc;
                sc.x = x[p * MODEL_DIMC + 128];
                sc.y = x[p * MODEL_DIMC + 129];
                *(float2*)&out[p * MODEL_DIMC + 128] = sc;
            }
        }
    }
}

extern "C" void kernel_launch(void* const* d_in, const int* in_sizes, int n_in,
                              void* d_out, int out_size, void* d_ws, size_t ws_size,
                              hipStream_t stream) {
    const float* x        = (const float*)d_in[0];
    const int*   nbr      = (const int*)  d_in[1];
    const float* basis    = (const float*)d_in[2];
    const float* disco_w  = (const float*)d_in[3];
    const float* disco_b  = (const float*)d_in[4];
    const float* head_w1  = (const float*)d_in[5];
    const float* head_b1  = (const float*)d_in[6];
    const float* head_w2  = (const float*)d_in[7];
    const float* head_b2  = (const float*)d_in[8];
    const float* ffn_w1   = (const float*)d_in[9];
    const float* ffn_b1   = (const float*)d_in[10];
    const float* ffn_w2   = (const float*)d_in[11];
    const float* ffn_b2   = (const float*)d_in[12];
    float* out = (float*)d_out;

    float* bw   = (float*)d_ws;                                   // [P][NNB][S] = 25.9 MB
    float* xmix = bw + (size_t)P_TOT * NNBC * S_DIM;              // [P][128]    = 8.3 MB

    hipLaunchKernelGGL(k1_bw, dim3((P_TOT * NNBC + 255) / 256), dim3(256), 0, stream,
                       basis, disco_w, bw);
    hipLaunchKernelGGL(k2_disco_head, dim3(P_TOT / 2), dim3(256), 0, stream,
                       x, nbr, bw, head_w1, head_b1, head_w2, head_b2, disco_b, xmix);
    hipLaunchKernelGGL(k3_ffn, dim3((P_TOT + 31) / 32), dim3(256), 0, stream,
                       x, xmix, ffn_w1, ffn_b1, ffn_w2, ffn_b2, out);
}